// Round 3
// baseline (126.302 us; speedup 1.0000x reference)
//
#include <hip/hip_runtime.h>
#include <stdint.h>

#define BB 8
#define SS 2048
#define DIN 768
#define DKV 64
#define NCHUNK (DIN / 32)   // 24 k-chunks of 32

typedef float f32x4 __attribute__((ext_vector_type(4)));
typedef __bf16 bf16x8 __attribute__((ext_vector_type(8)));

// ---------------------------------------------------------------------------
// Kernel 0: pre-convert W (f32, [64,768]) to bf16 MFMA-B fragment layout.
// ---------------------------------------------------------------------------
__global__ void wconv_kernel(const float* __restrict__ Wq,
                             const float* __restrict__ Wk,
                             const float* __restrict__ Wv,
                             __bf16* __restrict__ wf)
{
    const int m = blockIdx.y;
    const float* W = (m == 0) ? Wq : (m == 1) ? Wk : Wv;
    const int kc = blockIdx.x;
    const int t = threadIdx.x;
    const int c = t >> 6, lane = t & 63;
    const int lo = lane & 15, hi = lane >> 4;
    const float* src = W + (size_t)(16 * c + lo) * DIN + 32 * kc + 8 * hi;
    bf16x8 v;
    #pragma unroll
    for (int j = 0; j < 8; j++) v[j] = (__bf16)src[j];
    *(bf16x8*)(wf + ((((size_t)m * NCHUNK + kc) * 4 + c) * 64 + lane) * 8) = v;
}

// ---------------------------------------------------------------------------
// Kernel 1: fused projections (unchanged from round 2).
// ---------------------------------------------------------------------------
__global__ __launch_bounds__(256) void proj_kernel(
    const float* __restrict__ Aq, const float* __restrict__ Ak, const float* __restrict__ Av,
    const __bf16* __restrict__ wf,
    const float* __restrict__ bq, const float* __restrict__ bk, const float* __restrict__ bv,
    __bf16* __restrict__ q_ws, __bf16* __restrict__ k_ws, __bf16* __restrict__ vT_ws)
{
    const int which = blockIdx.y;
    const float* A; const float* bias;
    if (which == 0)      { A = Aq; bias = bq; }
    else if (which == 1) { A = Ak; bias = bk; }
    else                 { A = Av; bias = bv; }
    const __bf16* wfm = wf + (size_t)which * NCHUNK * 4 * 64 * 8;

    const int wave = threadIdx.x >> 6;
    const int lane = threadIdx.x & 63;
    const int lo = lane & 15, hi = lane >> 4;
    const int row = blockIdx.x * 64 + wave * 16 + lo;
    const float* arow = A + (size_t)row * DIN;

    #define LOADA(kc, a0, a1)  do { \
        a0 = *(const f32x4*)(arow + 32 * (kc) + 8 * hi); \
        a1 = *(const f32x4*)(arow + 32 * (kc) + 8 * hi + 4); } while (0)
    #define LOADW(kc, w)  do { \
        const __bf16* p_ = wfm + (((size_t)(kc) * 4 * 64) + lane) * 8; \
        w[0] = *(const bf16x8*)(p_); \
        w[1] = *(const bf16x8*)(p_ + 64 * 8); \
        w[2] = *(const bf16x8*)(p_ + 128 * 8); \
        w[3] = *(const bf16x8*)(p_ + 192 * 8); } while (0)
    #define CVT_MFMA(a0, a1, w, acc)  do { \
        bf16x8 af_; \
        _Pragma("unroll") \
        for (int j_ = 0; j_ < 4; j_++) { af_[j_] = (__bf16)a0[j_]; af_[4 + j_] = (__bf16)a1[j_]; } \
        _Pragma("unroll") \
        for (int c_ = 0; c_ < 4; c_++) \
            acc[c_] = __builtin_amdgcn_mfma_f32_16x16x32_bf16(af_, w[c_], acc[c_], 0, 0, 0); \
    } while (0)

    f32x4 a0A, a1A, a0B, a1B;
    bf16x8 wA[4], wB[4];
    LOADA(0, a0A, a1A); LOADW(0, wA);
    LOADA(1, a0B, a1B); LOADW(1, wB);

    f32x4 acc[4] = {};

    #pragma unroll 1
    for (int kc = 0; kc < NCHUNK; kc += 2) {
        const int pkA = (kc + 2 < NCHUNK) ? kc + 2 : kc;
        f32x4 n0A, n1A; bf16x8 nwA[4];
        LOADA(pkA, n0A, n1A); LOADW(pkA, nwA);

        CVT_MFMA(a0A, a1A, wA, acc);

        const int pkB = (kc + 3 < NCHUNK) ? kc + 3 : kc + 1;
        f32x4 n0B, n1B; bf16x8 nwB[4];
        LOADA(pkB, n0B, n1B); LOADW(pkB, nwB);

        CVT_MFMA(a0B, a1B, wB, acc);

        a0A = n0A; a1A = n1A; a0B = n0B; a1B = n1B;
        #pragma unroll
        for (int c = 0; c < 4; c++) { wA[c] = nwA[c]; wB[c] = nwB[c]; }
    }

    const int orow_base = blockIdx.x * 64 + wave * 16 + 4 * hi;
    #pragma unroll
    for (int c = 0; c < 4; c++) {
        const int col = lo + 16 * c;
        const float bcol = bias[col];
        #pragma unroll
        for (int r = 0; r < 4; r++) {
            const int orow = orow_base + r;
            const float val = acc[c][r] + bcol;
            const int b = orow >> 11;
            const int s = orow & 2047;
            if (which == 0)      q_ws[((size_t)b * SS + s) * DKV + col] = (__bf16)val;
            else if (which == 1) k_ws[((size_t)b * SS + s) * DKV + col] = (__bf16)val;
            else                 vT_ws[((size_t)b * DKV + col) * SS + s] = (__bf16)val;
        }
    }
    #undef LOADA
    #undef LOADW
    #undef CVT_MFMA
}

// ---------------------------------------------------------------------------
// Kernel 2: flash attention, within-block KV split for occupancy.
// Block = 512 threads (8 waves), ONE 16-row q-tile; wave w owns keys
// [w*256, w*256+256) = 4 iters of 64.  Flash combine across waves in LDS.
// LDS phase-union: main {mask 8K, P 18K} / combine {ml 1K, o[8][16][65] 33K}.
// ---------------------------------------------------------------------------
#define NW 8
#define KPW (SS / NW)       // 256 keys per wave

__global__ __launch_bounds__(512, 8) void attn_kernel(
    const __bf16* __restrict__ q_ws, const __bf16* __restrict__ k_ws,
    const __bf16* __restrict__ vT_ws, const int* __restrict__ mask,
    float* __restrict__ out)
{
    __shared__ __align__(16) char smem[34304];
    // main phase
    int* mask_lds = (int*)smem;                                        // 8192 B
    __bf16 (*p_lds)[16][72] = (__bf16(*)[16][72])(smem + 8192);        // 18432 B
    // combine phase (after sync, main-phase data dead)
    float (*ml_lds)[2][16] = (float(*)[2][16])smem;                    // 1024 B
    float (*o_lds)[16][65] = (float(*)[16][65])(smem + 1024);          // 33280 B

    const int b = blockIdx.y;
    const int qbase = blockIdx.x * 16;
    const int w = threadIdx.x >> 6;
    const int lane = threadIdx.x & 63;
    const int lo = lane & 15, hi = lane >> 4;

    for (int i = threadIdx.x; i < SS; i += 512) mask_lds[i] = mask[b * SS + i];
    __syncthreads();

    const __bf16* qp = q_ws + ((size_t)b * SS + qbase + lo) * DKV;
    bf16x8 qf0 = *(const bf16x8*)(qp + 8 * hi);
    bf16x8 qf1 = *(const bf16x8*)(qp + 32 + 8 * hi);

    f32x4 oacc[4] = {};
    float m[4], l[4];
    #pragma unroll
    for (int r = 0; r < 4; r++) { m[r] = -1e30f; l[r] = 0.f; }

    #pragma unroll 1
    for (int it = 0; it < KPW / 64; ++it) {
        const int kv = w * KPW + it * 64;

        // ---- QK^T for 64 keys ----
        f32x4 sacc[4] = {};
        #pragma unroll
        for (int sub = 0; sub < 4; sub++) {
            const __bf16* kp = k_ws + ((size_t)b * SS + kv + sub * 16 + lo) * DKV;
            bf16x8 kf0 = *(const bf16x8*)(kp + 8 * hi);
            bf16x8 kf1 = *(const bf16x8*)(kp + 32 + 8 * hi);
            sacc[sub] = __builtin_amdgcn_mfma_f32_16x16x32_bf16(qf0, kf0, sacc[sub], 0, 0, 0);
            sacc[sub] = __builtin_amdgcn_mfma_f32_16x16x32_bf16(qf1, kf1, sacc[sub], 0, 0, 0);
        }

        // ---- scale + mask ----
        float s_val[4][4];
        #pragma unroll
        for (int sub = 0; sub < 4; sub++) {
            const int key = kv + sub * 16 + lo;
            const bool msk = (mask_lds[key] != 0);
            #pragma unroll
            for (int r = 0; r < 4; r++)
                s_val[sub][r] = msk ? -1e30f : sacc[sub][r] * 0.125f;
        }

        // ---- row-max across lo lanes ----
        float cm[4];
        #pragma unroll
        for (int r = 0; r < 4; r++) {
            float v0 = fmaxf(fmaxf(s_val[0][r], s_val[1][r]),
                             fmaxf(s_val[2][r], s_val[3][r]));
            v0 = fmaxf(v0, __shfl_xor(v0, 1));
            v0 = fmaxf(v0, __shfl_xor(v0, 2));
            v0 = fmaxf(v0, __shfl_xor(v0, 4));
            v0 = fmaxf(v0, __shfl_xor(v0, 8));
            cm[r] = v0;
        }

        // ---- online-softmax update ----
        #pragma unroll
        for (int r = 0; r < 4; r++) {
            const float mnew = fmaxf(m[r], cm[r]);
            const float alpha = __expf(m[r] - mnew);
            m[r] = mnew;
            l[r] *= alpha;
            #pragma unroll
            for (int c = 0; c < 4; c++) oacc[c][r] *= alpha;
        }

        // ---- P = exp(s-m); lane-partial l; bounce to LDS ----
        #pragma unroll
        for (int sub = 0; sub < 4; sub++) {
            #pragma unroll
            for (int r = 0; r < 4; r++) {
                const float p = __expf(s_val[sub][r] - m[r]);
                l[r] += p;
                p_lds[w][4 * hi + r][sub * 16 + lo] = (__bf16)p;
            }
        }
        asm volatile("s_waitcnt lgkmcnt(0)" ::: "memory");

        // ---- PV ----
        bf16x8 pa0 = *(const bf16x8*)&p_lds[w][lo][8 * hi];
        bf16x8 pa1 = *(const bf16x8*)&p_lds[w][lo][32 + 8 * hi];
        #pragma unroll
        for (int c = 0; c < 4; c++) {
            const __bf16* vp = vT_ws + ((size_t)b * DKV + 16 * c + lo) * SS + kv;
            bf16x8 vf0 = *(const bf16x8*)(vp + 8 * hi);
            bf16x8 vf1 = *(const bf16x8*)(vp + 32 + 8 * hi);
            oacc[c] = __builtin_amdgcn_mfma_f32_16x16x32_bf16(pa0, vf0, oacc[c], 0, 0, 0);
            oacc[c] = __builtin_amdgcn_mfma_f32_16x16x32_bf16(pa1, vf1, oacc[c], 0, 0, 0);
        }
    }

    // ---- reduce l across lo lanes ----
    #pragma unroll
    for (int r = 0; r < 4; r++) {
        float lv = l[r];
        lv += __shfl_xor(lv, 1);
        lv += __shfl_xor(lv, 2);
        lv += __shfl_xor(lv, 4);
        lv += __shfl_xor(lv, 8);
        l[r] = lv;
    }

    __syncthreads();   // main-phase LDS reads complete; safe to repurpose

    // ---- publish per-wave partials ----
    if (lo == 0) {
        #pragma unroll
        for (int r = 0; r < 4; r++) {
            ml_lds[w][0][4 * hi + r] = m[r];
            ml_lds[w][1][4 * hi + r] = l[r];
        }
    }
    #pragma unroll
    for (int c = 0; c < 4; c++)
        #pragma unroll
        for (int r = 0; r < 4; r++)
            o_lds[w][4 * hi + r][16 * c + lo] = oacc[c][r];
    __syncthreads();

    // ---- cross-wave flash combine: 1024 cells / 512 threads = 2 each ----
    for (int idx = threadIdx.x; idx < 16 * 64; idx += 512) {
        const int row = idx >> 6, col = idx & 63;
        float M = -1e30f;
        #pragma unroll
        for (int w8 = 0; w8 < NW; w8++) M = fmaxf(M, ml_lds[w8][0][row]);
        float L = 0.f, osum = 0.f;
        #pragma unroll
        for (int w8 = 0; w8 < NW; w8++) {
            const float a = __expf(ml_lds[w8][0][row] - M);
            L += ml_lds[w8][1][row] * a;
            osum += o_lds[w8][row][col] * a;
        }
        out[((size_t)b * SS + qbase + row) * DKV + col] = osum / L;
    }
}

extern "C" void kernel_launch(void* const* d_in, const int* in_sizes, int n_in,
                              void* d_out, int out_size, void* d_ws, size_t ws_size,
                              hipStream_t stream)
{
    (void)in_sizes; (void)n_in; (void)out_size; (void)ws_size;
    const float* query = (const float*)d_in[0];
    const float* key_  = (const float*)d_in[1];
    const float* value = (const float*)d_in[2];
    const int*   mask  = (const int*)d_in[3];
    const float* Wq    = (const float*)d_in[4];
    const float* bq    = (const float*)d_in[5];
    const float* Wk    = (const float*)d_in[6];
    const float* bk    = (const float*)d_in[7];
    const float* Wv    = (const float*)d_in[8];
    const float* bv    = (const float*)d_in[9];
    float* out = (float*)d_out;

    __bf16* q_ws  = (__bf16*)d_ws;                         // 2 MB
    __bf16* k_ws  = q_ws + (size_t)BB * SS * DKV;          // 2 MB
    __bf16* vT_ws = k_ws + (size_t)BB * SS * DKV;          // 2 MB (transposed)
    __bf16* wf    = vT_ws + (size_t)BB * SS * DKV;         // 3 x 98 KB frag-W

    wconv_kernel<<<dim3(NCHUNK, 3, 1), 256, 0, stream>>>(Wq, Wk, Wv, wf);
    proj_kernel<<<dim3(256, 3, 1), 256, 0, stream>>>(
        query, key_, value, wf, bq, bk, bv, q_ws, k_ws, vT_ws);
    attn_kernel<<<dim3(SS / 16, BB, 1), 512, 0, stream>>>(
        q_ws, k_ws, vT_ws, mask, out);
}

// Round 4
// 101.737 us; speedup vs baseline: 1.2414x; 1.2414x over previous
//
#include <hip/hip_runtime.h>
#include <stdint.h>

#define BB 8
#define SS 2048
#define DIN 768
#define DKV 64
#define NCHUNK (DIN / 32)   // 24 k-chunks of 32

typedef float f32x4 __attribute__((ext_vector_type(4)));
typedef __bf16 bf16x8 __attribute__((ext_vector_type(8)));

// ---------------------------------------------------------------------------
// Kernel 0: pre-convert W (f32, [64,768]) to bf16 MFMA-B fragment layout.
// ---------------------------------------------------------------------------
__global__ void wconv_kernel(const float* __restrict__ Wq,
                             const float* __restrict__ Wk,
                             const float* __restrict__ Wv,
                             __bf16* __restrict__ wf)
{
    const int m = blockIdx.y;
    const float* W = (m == 0) ? Wq : (m == 1) ? Wk : Wv;
    const int kc = blockIdx.x;
    const int t = threadIdx.x;
    const int c = t >> 6, lane = t & 63;
    const int lo = lane & 15, hi = lane >> 4;
    const float* src = W + (size_t)(16 * c + lo) * DIN + 32 * kc + 8 * hi;
    bf16x8 v;
    #pragma unroll
    for (int j = 0; j < 8; j++) v[j] = (__bf16)src[j];
    *(bf16x8*)(wf + ((((size_t)m * NCHUNK + kc) * 4 + c) * 64 + lane) * 8) = v;
}

// ---------------------------------------------------------------------------
// Kernel 1: fused projections (unchanged).
// ---------------------------------------------------------------------------
__global__ __launch_bounds__(256) void proj_kernel(
    const float* __restrict__ Aq, const float* __restrict__ Ak, const float* __restrict__ Av,
    const __bf16* __restrict__ wf,
    const float* __restrict__ bq, const float* __restrict__ bk, const float* __restrict__ bv,
    __bf16* __restrict__ q_ws, __bf16* __restrict__ k_ws, __bf16* __restrict__ vT_ws)
{
    const int which = blockIdx.y;
    const float* A; const float* bias;
    if (which == 0)      { A = Aq; bias = bq; }
    else if (which == 1) { A = Ak; bias = bk; }
    else                 { A = Av; bias = bv; }
    const __bf16* wfm = wf + (size_t)which * NCHUNK * 4 * 64 * 8;

    const int wave = threadIdx.x >> 6;
    const int lane = threadIdx.x & 63;
    const int lo = lane & 15, hi = lane >> 4;
    const int row = blockIdx.x * 64 + wave * 16 + lo;
    const float* arow = A + (size_t)row * DIN;

    #define LOADA(kc, a0, a1)  do { \
        a0 = *(const f32x4*)(arow + 32 * (kc) + 8 * hi); \
        a1 = *(const f32x4*)(arow + 32 * (kc) + 8 * hi + 4); } while (0)
    #define LOADW(kc, w)  do { \
        const __bf16* p_ = wfm + (((size_t)(kc) * 4 * 64) + lane) * 8; \
        w[0] = *(const bf16x8*)(p_); \
        w[1] = *(const bf16x8*)(p_ + 64 * 8); \
        w[2] = *(const bf16x8*)(p_ + 128 * 8); \
        w[3] = *(const bf16x8*)(p_ + 192 * 8); } while (0)
    #define CVT_MFMA(a0, a1, w, acc)  do { \
        bf16x8 af_; \
        _Pragma("unroll") \
        for (int j_ = 0; j_ < 4; j_++) { af_[j_] = (__bf16)a0[j_]; af_[4 + j_] = (__bf16)a1[j_]; } \
        _Pragma("unroll") \
        for (int c_ = 0; c_ < 4; c_++) \
            acc[c_] = __builtin_amdgcn_mfma_f32_16x16x32_bf16(af_, w[c_], acc[c_], 0, 0, 0); \
    } while (0)

    f32x4 a0A, a1A, a0B, a1B;
    bf16x8 wA[4], wB[4];
    LOADA(0, a0A, a1A); LOADW(0, wA);
    LOADA(1, a0B, a1B); LOADW(1, wB);

    f32x4 acc[4] = {};

    #pragma unroll 1
    for (int kc = 0; kc < NCHUNK; kc += 2) {
        const int pkA = (kc + 2 < NCHUNK) ? kc + 2 : kc;
        f32x4 n0A, n1A; bf16x8 nwA[4];
        LOADA(pkA, n0A, n1A); LOADW(pkA, nwA);

        CVT_MFMA(a0A, a1A, wA, acc);

        const int pkB = (kc + 3 < NCHUNK) ? kc + 3 : kc + 1;
        f32x4 n0B, n1B; bf16x8 nwB[4];
        LOADA(pkB, n0B, n1B); LOADW(pkB, nwB);

        CVT_MFMA(a0B, a1B, wB, acc);

        a0A = n0A; a1A = n1A; a0B = n0B; a1B = n1B;
        #pragma unroll
        for (int c = 0; c < 4; c++) { wA[c] = nwA[c]; wB[c] = nwB[c]; }
    }

    const int orow_base = blockIdx.x * 64 + wave * 16 + 4 * hi;
    #pragma unroll
    for (int c = 0; c < 4; c++) {
        const int col = lo + 16 * c;
        const float bcol = bias[col];
        #pragma unroll
        for (int r = 0; r < 4; r++) {
            const int orow = orow_base + r;
            const float val = acc[c][r] + bcol;
            const int b = orow >> 11;
            const int s = orow & 2047;
            if (which == 0)      q_ws[((size_t)b * SS + s) * DKV + col] = (__bf16)val;
            else if (which == 1) k_ws[((size_t)b * SS + s) * DKV + col] = (__bf16)val;
            else                 vT_ws[((size_t)b * DKV + col) * SS + s] = (__bf16)val;
        }
    }
    #undef LOADA
    #undef LOADW
    #undef CVT_MFMA
}

// ---------------------------------------------------------------------------
// Kernel 2: flash attention, within-block KV split.
// Block = 512 thr (8 waves), ONE 16-row q-tile; wave w owns keys
// [w*256, w*256+256) as 4 iters of 64.  Flash combine across waves in LDS.
// launch_bounds(512,4): 128-VGPR cap -> no spill (r3 lesson: (512,8) forced
// VGPR=32 + 86MB scratch).  Grid flat 1024; b = bid&7 pins batch<->XCD so
// each XCD's L2 holds its batch's K+V (512 KB).
// ---------------------------------------------------------------------------
#define NW 8
#define KPW (SS / NW)       // 256 keys per wave

__global__ __launch_bounds__(512, 4) void attn_kernel(
    const __bf16* __restrict__ q_ws, const __bf16* __restrict__ k_ws,
    const __bf16* __restrict__ vT_ws, const int* __restrict__ mask,
    float* __restrict__ out)
{
    __shared__ __align__(16) char smem[34304];
    // main phase
    int* mask_lds = (int*)smem;                                        // 8192 B
    __bf16 (*p_lds)[16][72] = (__bf16(*)[16][72])(smem + 8192);        // 18432 B
    // combine phase (after sync, main-phase data dead)
    float (*ml_lds)[2][16] = (float(*)[2][16])smem;                    // 1024 B
    float (*o_lds)[16][65] = (float(*)[16][65])(smem + 1024);          // 33280 B

    const int b = blockIdx.x & 7;          // batch == XCD (round-robin dispatch)
    const int qbase = (blockIdx.x >> 3) * 16;
    const int w = threadIdx.x >> 6;
    const int lane = threadIdx.x & 63;
    const int lo = lane & 15, hi = lane >> 4;

    for (int i = threadIdx.x; i < SS; i += 512) mask_lds[i] = mask[b * SS + i];
    __syncthreads();

    const __bf16* qp = q_ws + ((size_t)b * SS + qbase + lo) * DKV;
    bf16x8 qf0 = *(const bf16x8*)(qp + 8 * hi);
    bf16x8 qf1 = *(const bf16x8*)(qp + 32 + 8 * hi);

    f32x4 oacc[4] = {};
    float m[4], l[4];
    #pragma unroll
    for (int r = 0; r < 4; r++) { m[r] = -1e30f; l[r] = 0.f; }

    #pragma unroll 1
    for (int it = 0; it < KPW / 64; ++it) {
        const int kv = w * KPW + it * 64;

        // ---- issue K AND V loads up front (V latency hides under QK+softmax) ----
        bf16x8 kf[8], vf[8];
        #pragma unroll
        for (int sub = 0; sub < 4; sub++) {
            const __bf16* kp = k_ws + ((size_t)b * SS + kv + sub * 16 + lo) * DKV;
            kf[2 * sub]     = *(const bf16x8*)(kp + 8 * hi);
            kf[2 * sub + 1] = *(const bf16x8*)(kp + 32 + 8 * hi);
        }
        #pragma unroll
        for (int c = 0; c < 4; c++) {
            const __bf16* vp = vT_ws + ((size_t)b * DKV + 16 * c + lo) * SS + kv;
            vf[2 * c]     = *(const bf16x8*)(vp + 8 * hi);
            vf[2 * c + 1] = *(const bf16x8*)(vp + 32 + 8 * hi);
        }

        // ---- QK^T ----
        f32x4 sacc[4] = {};
        #pragma unroll
        for (int sub = 0; sub < 4; sub++) {
            sacc[sub] = __builtin_amdgcn_mfma_f32_16x16x32_bf16(qf0, kf[2 * sub],     sacc[sub], 0, 0, 0);
            sacc[sub] = __builtin_amdgcn_mfma_f32_16x16x32_bf16(qf1, kf[2 * sub + 1], sacc[sub], 0, 0, 0);
        }

        // ---- scale + mask in place ----
        #pragma unroll
        for (int sub = 0; sub < 4; sub++) {
            const bool msk = (mask_lds[kv + sub * 16 + lo] != 0);
            #pragma unroll
            for (int r = 0; r < 4; r++)
                sacc[sub][r] = msk ? -1e30f : sacc[sub][r] * 0.125f;
        }

        // ---- row-max across lo lanes ----
        float cm[4];
        #pragma unroll
        for (int r = 0; r < 4; r++) {
            float v0 = fmaxf(fmaxf(sacc[0][r], sacc[1][r]),
                             fmaxf(sacc[2][r], sacc[3][r]));
            v0 = fmaxf(v0, __shfl_xor(v0, 1));
            v0 = fmaxf(v0, __shfl_xor(v0, 2));
            v0 = fmaxf(v0, __shfl_xor(v0, 4));
            v0 = fmaxf(v0, __shfl_xor(v0, 8));
            cm[r] = v0;
        }

        // ---- online-softmax update ----
        #pragma unroll
        for (int r = 0; r < 4; r++) {
            const float mnew = fmaxf(m[r], cm[r]);
            const float alpha = __expf(m[r] - mnew);
            m[r] = mnew;
            l[r] *= alpha;
            #pragma unroll
            for (int c = 0; c < 4; c++) oacc[c][r] *= alpha;
        }

        // ---- P = exp(s-m); lane-partial l; bounce to LDS ----
        #pragma unroll
        for (int sub = 0; sub < 4; sub++) {
            #pragma unroll
            for (int r = 0; r < 4; r++) {
                const float p = __expf(sacc[sub][r] - m[r]);
                l[r] += p;
                p_lds[w][4 * hi + r][sub * 16 + lo] = (__bf16)p;
            }
        }
        asm volatile("s_waitcnt lgkmcnt(0)" ::: "memory");

        // ---- PV (V already in registers) ----
        bf16x8 pa0 = *(const bf16x8*)&p_lds[w][lo][8 * hi];
        bf16x8 pa1 = *(const bf16x8*)&p_lds[w][lo][32 + 8 * hi];
        #pragma unroll
        for (int c = 0; c < 4; c++) {
            oacc[c] = __builtin_amdgcn_mfma_f32_16x16x32_bf16(pa0, vf[2 * c],     oacc[c], 0, 0, 0);
            oacc[c] = __builtin_amdgcn_mfma_f32_16x16x32_bf16(pa1, vf[2 * c + 1], oacc[c], 0, 0, 0);
        }
    }

    // ---- reduce l across lo lanes ----
    #pragma unroll
    for (int r = 0; r < 4; r++) {
        float lv = l[r];
        lv += __shfl_xor(lv, 1);
        lv += __shfl_xor(lv, 2);
        lv += __shfl_xor(lv, 4);
        lv += __shfl_xor(lv, 8);
        l[r] = lv;
    }

    __syncthreads();   // main-phase LDS reads complete; safe to repurpose

    // ---- publish per-wave partials ----
    if (lo == 0) {
        #pragma unroll
        for (int r = 0; r < 4; r++) {
            ml_lds[w][0][4 * hi + r] = m[r];
            ml_lds[w][1][4 * hi + r] = l[r];
        }
    }
    #pragma unroll
    for (int c = 0; c < 4; c++)
        #pragma unroll
        for (int r = 0; r < 4; r++)
            o_lds[w][4 * hi + r][16 * c + lo] = oacc[c][r];
    __syncthreads();

    // ---- cross-wave flash combine ----
    for (int idx = threadIdx.x; idx < 16 * 64; idx += 512) {
        const int row = idx >> 6, col = idx & 63;
        float M = -1e30f;
        #pragma unroll
        for (int w8 = 0; w8 < NW; w8++) M = fmaxf(M, ml_lds[w8][0][row]);
        float L = 0.f, osum = 0.f;
        #pragma unroll
        for (int w8 = 0; w8 < NW; w8++) {
            const float a = __expf(ml_lds[w8][0][row] - M);
            L += ml_lds[w8][1][row] * a;
            osum += o_lds[w8][row][col] * a;
        }
        out[((size_t)b * SS + qbase + row) * DKV + col] = osum / L;
    }
}

extern "C" void kernel_launch(void* const* d_in, const int* in_sizes, int n_in,
                              void* d_out, int out_size, void* d_ws, size_t ws_size,
                              hipStream_t stream)
{
    (void)in_sizes; (void)n_in; (void)out_size; (void)ws_size;
    const float* query = (const float*)d_in[0];
    const float* key_  = (const float*)d_in[1];
    const float* value = (const float*)d_in[2];
    const int*   mask  = (const int*)d_in[3];
    const float* Wq    = (const float*)d_in[4];
    const float* bq    = (const float*)d_in[5];
    const float* Wk    = (const float*)d_in[6];
    const float* bk    = (const float*)d_in[7];
    const float* Wv    = (const float*)d_in[8];
    const float* bv    = (const float*)d_in[9];
    float* out = (float*)d_out;

    __bf16* q_ws  = (__bf16*)d_ws;                         // 2 MB
    __bf16* k_ws  = q_ws + (size_t)BB * SS * DKV;          // 2 MB
    __bf16* vT_ws = k_ws + (size_t)BB * SS * DKV;          // 2 MB (transposed)
    __bf16* wf    = vT_ws + (size_t)BB * SS * DKV;         // 3 x 98 KB frag-W

    wconv_kernel<<<dim3(NCHUNK, 3, 1), 256, 0, stream>>>(Wq, Wk, Wv, wf);
    proj_kernel<<<dim3(256, 3, 1), 256, 0, stream>>>(
        query, key_, value, wf, bq, bk, bv, q_ws, k_ws, vT_ws);
    attn_kernel<<<dim3(SS / 16 * BB, 1, 1), 512, 0, stream>>>(
        q_ws, k_ws, vT_ws, mask, out);
}

// Round 5
// 76.897 us; speedup vs baseline: 1.6425x; 1.3230x over previous
//
#include <hip/hip_runtime.h>
#include <stdint.h>

#define BB 8
#define SS 2048
#define DIN 768
#define DKV 64
#define NCHUNK (DIN / 32)   // 24 k-chunks of 32

typedef float f32x4 __attribute__((ext_vector_type(4)));
typedef float f32x16 __attribute__((ext_vector_type(16)));
typedef __bf16 bf16x8 __attribute__((ext_vector_type(8)));

// ---------------------------------------------------------------------------
// Kernel 0: pre-convert W (f32, [64,768]) to bf16 MFMA-B fragment layout.
// ---------------------------------------------------------------------------
__global__ void wconv_kernel(const float* __restrict__ Wq,
                             const float* __restrict__ Wk,
                             const float* __restrict__ Wv,
                             __bf16* __restrict__ wf)
{
    const int m = blockIdx.y;
    const float* W = (m == 0) ? Wq : (m == 1) ? Wk : Wv;
    const int kc = blockIdx.x;
    const int t = threadIdx.x;
    const int c = t >> 6, lane = t & 63;
    const int lo = lane & 15, hi = lane >> 4;
    const float* src = W + (size_t)(16 * c + lo) * DIN + 32 * kc + 8 * hi;
    bf16x8 v;
    #pragma unroll
    for (int j = 0; j < 8; j++) v[j] = (__bf16)src[j];
    *(bf16x8*)(wf + ((((size_t)m * NCHUNK + kc) * 4 + c) * 64 + lane) * 8) = v;
}

// ---------------------------------------------------------------------------
// Kernel 1: fused projections (unchanged from round 4).
// ---------------------------------------------------------------------------
__global__ __launch_bounds__(256) void proj_kernel(
    const float* __restrict__ Aq, const float* __restrict__ Ak, const float* __restrict__ Av,
    const __bf16* __restrict__ wf,
    const float* __restrict__ bq, const float* __restrict__ bk, const float* __restrict__ bv,
    __bf16* __restrict__ q_ws, __bf16* __restrict__ k_ws, __bf16* __restrict__ vT_ws)
{
    const int which = blockIdx.y;
    const float* A; const float* bias;
    if (which == 0)      { A = Aq; bias = bq; }
    else if (which == 1) { A = Ak; bias = bk; }
    else                 { A = Av; bias = bv; }
    const __bf16* wfm = wf + (size_t)which * NCHUNK * 4 * 64 * 8;

    const int wave = threadIdx.x >> 6;
    const int lane = threadIdx.x & 63;
    const int lo = lane & 15, hi = lane >> 4;
    const int row = blockIdx.x * 64 + wave * 16 + lo;
    const float* arow = A + (size_t)row * DIN;

    #define LOADA(kc, a0, a1)  do { \
        a0 = *(const f32x4*)(arow + 32 * (kc) + 8 * hi); \
        a1 = *(const f32x4*)(arow + 32 * (kc) + 8 * hi + 4); } while (0)
    #define LOADW(kc, w)  do { \
        const __bf16* p_ = wfm + (((size_t)(kc) * 4 * 64) + lane) * 8; \
        w[0] = *(const bf16x8*)(p_); \
        w[1] = *(const bf16x8*)(p_ + 64 * 8); \
        w[2] = *(const bf16x8*)(p_ + 128 * 8); \
        w[3] = *(const bf16x8*)(p_ + 192 * 8); } while (0)
    #define CVT_MFMA(a0, a1, w, acc)  do { \
        bf16x8 af_; \
        _Pragma("unroll") \
        for (int j_ = 0; j_ < 4; j_++) { af_[j_] = (__bf16)a0[j_]; af_[4 + j_] = (__bf16)a1[j_]; } \
        _Pragma("unroll") \
        for (int c_ = 0; c_ < 4; c_++) \
            acc[c_] = __builtin_amdgcn_mfma_f32_16x16x32_bf16(af_, w[c_], acc[c_], 0, 0, 0); \
    } while (0)

    f32x4 a0A, a1A, a0B, a1B;
    bf16x8 wA[4], wB[4];
    LOADA(0, a0A, a1A); LOADW(0, wA);
    LOADA(1, a0B, a1B); LOADW(1, wB);

    f32x4 acc[4] = {};

    #pragma unroll 1
    for (int kc = 0; kc < NCHUNK; kc += 2) {
        const int pkA = (kc + 2 < NCHUNK) ? kc + 2 : kc;
        f32x4 n0A, n1A; bf16x8 nwA[4];
        LOADA(pkA, n0A, n1A); LOADW(pkA, nwA);

        CVT_MFMA(a0A, a1A, wA, acc);

        const int pkB = (kc + 3 < NCHUNK) ? kc + 3 : kc + 1;
        f32x4 n0B, n1B; bf16x8 nwB[4];
        LOADA(pkB, n0B, n1B); LOADW(pkB, nwB);

        CVT_MFMA(a0B, a1B, wB, acc);

        a0A = n0A; a1A = n1A; a0B = n0B; a1B = n1B;
        #pragma unroll
        for (int c = 0; c < 4; c++) { wA[c] = nwA[c]; wB[c] = nwB[c]; }
    }

    const int orow_base = blockIdx.x * 64 + wave * 16 + 4 * hi;
    #pragma unroll
    for (int c = 0; c < 4; c++) {
        const int col = lo + 16 * c;
        const float bcol = bias[col];
        #pragma unroll
        for (int r = 0; r < 4; r++) {
            const int orow = orow_base + r;
            const float val = acc[c][r] + bcol;
            const int b = orow >> 11;
            const int s = orow & 2047;
            if (which == 0)      q_ws[((size_t)b * SS + s) * DKV + col] = (__bf16)val;
            else if (which == 1) k_ws[((size_t)b * SS + s) * DKV + col] = (__bf16)val;
            else                 vT_ws[((size_t)b * DKV + col) * SS + s] = (__bf16)val;
        }
    }
    #undef LOADA
    #undef LOADW
    #undef CVT_MFMA
}

// ---------------------------------------------------------------------------
// Kernel 2: flash attention v3 — swapped QK^T (mfma(K,Q) -> D[key][q]) with
// 32x32x16 MFMA.  Each lane owns ONE q (col=lane&31) and 16 key-scores in
// regs -> softmax fully in-register (tree max + 1 shfl_xor(32)), m/l scalar.
// Mask folded into MFMA C-init as -8e30 bias (f32 absorption -> all-masked
// rows exactly uniform, matching reference).  exp2-domain, scale in CEXP.
// P->PV B-frag: pack bf16 pairs, 1 shfl_xor(32) per word-pair, cndmask.
// Block = 8 waves x (32q x 256 keys); flash-combine across waves in LDS.
// ---------------------------------------------------------------------------
#define NW 8
#define CEXP 0.18033688011f    // 0.125 * log2(e)

__device__ inline uint32_t pk2(float a, float b) {
    union { __bf16 h[2]; uint32_t u; } z;
    z.h[0] = (__bf16)a; z.h[1] = (__bf16)b;
    return z.u;
}

__global__ __launch_bounds__(512, 4) void attn_kernel(
    const __bf16* __restrict__ q_ws, const __bf16* __restrict__ k_ws,
    const __bf16* __restrict__ vT_ws, const int* __restrict__ mask,
    float* __restrict__ out)
{
    __shared__ float bias_lds[SS];          // 8 KB   (bias*8: 0 or -8e30)
    __shared__ float ml_lds[NW][2][32];     // 2 KB
    __shared__ float o_lds[NW][32][66];     // 67.6 KB (pad 66: 2-way free)

    const int b = blockIdx.x & 7;              // batch == XCD (round-robin)
    const int qbase = (blockIdx.x >> 3) * 32;
    const int w = threadIdx.x >> 6;
    const int lane = threadIdx.x & 63;
    const int lq = lane & 31;                  // q for B-col / key,v for A-row
    const int h = lane >> 5;

    for (int i = threadIdx.x; i < SS; i += 512)
        bias_lds[i] = mask[b * SS + i] ? -8e30f : 0.0f;
    __syncthreads();

    // Q B-frags (persist): qbf[t][j] = Q[qbase+lq][16t + 8h + j]
    bf16x8 qbf[4];
    {
        const __bf16* qp = q_ws + ((size_t)b * SS + qbase + lq) * DKV + 8 * h;
        #pragma unroll
        for (int t = 0; t < 4; t++) qbf[t] = *(const bf16x8*)(qp + 16 * t);
    }

    f32x16 oacc0 = {}, oacc1 = {};   // D[v][q], v-halves 0-31 / 32-63
    float m = -3e38f, l = 0.f;       // per-lane: one q, own key-subset l

    #pragma unroll 1
    for (int it = 0; it < 8; ++it) {
        const int kv = w * 256 + it * 32;

        // ---- C-init = mask bias: acc[r] <- bias8[kv + 8*(r>>2) + 4h + (r&3)]
        f32x16 acc;
        #pragma unroll
        for (int g = 0; g < 4; g++) {
            f32x4 bg = *(const f32x4*)&bias_lds[kv + 8 * g + 4 * h];
            acc[4*g+0] = bg[0]; acc[4*g+1] = bg[1];
            acc[4*g+2] = bg[2]; acc[4*g+3] = bg[3];
        }

        // ---- QK^T: D[key][q], 4 d-steps of 16
        const __bf16* kp = k_ws + ((size_t)b * SS + kv + lq) * DKV + 8 * h;
        #pragma unroll
        for (int t = 0; t < 4; t++) {
            bf16x8 kaf = *(const bf16x8*)(kp + 16 * t);
            acc = __builtin_amdgcn_mfma_f32_32x32x16_bf16(kaf, qbf[t], acc, 0, 0, 0);
        }

        // ---- in-register block max (own 16 + partner half)
        float q0 = fmaxf(fmaxf(acc[0], acc[1]),  fmaxf(acc[2], acc[3]));
        float q1 = fmaxf(fmaxf(acc[4], acc[5]),  fmaxf(acc[6], acc[7]));
        float q2 = fmaxf(fmaxf(acc[8], acc[9]),  fmaxf(acc[10], acc[11]));
        float q3 = fmaxf(fmaxf(acc[12], acc[13]), fmaxf(acc[14], acc[15]));
        float mx = fmaxf(fmaxf(q0, q1), fmaxf(q2, q3));
        mx = fmaxf(mx, __shfl_xor(mx, 32));

        const float mnew = fmaxf(m, mx);
        const float alpha = exp2f((m - mnew) * CEXP);
        m = mnew;
        l *= alpha;
        #pragma unroll
        for (int r = 0; r < 16; r++) { oacc0[r] *= alpha; oacc1[r] *= alpha; }

        float p[16];
        #pragma unroll
        for (int r = 0; r < 16; r++) {
            p[r] = exp2f((acc[r] - mnew) * CEXP);
            l += p[r];
        }

        // ---- pack + half-exchange + PV (2 k-steps of 16 keys)
        #pragma unroll
        for (int s = 0; s < 2; s++) {
            const uint32_t X0 = pk2(p[8*s+0], p[8*s+1]);
            const uint32_t X1 = pk2(p[8*s+2], p[8*s+3]);
            const uint32_t Y0 = pk2(p[8*s+4], p[8*s+5]);
            const uint32_t Y1 = pk2(p[8*s+6], p[8*s+7]);
            const uint32_t s0 = h ? X0 : Y0;       // send what partner needs
            const uint32_t s1 = h ? X1 : Y1;
            const uint32_t c0 = __shfl_xor(s0, 32);
            const uint32_t c1 = __shfl_xor(s1, 32);
            union { uint32_t wd[4]; bf16x8 v; } fr;
            fr.wd[0] = h ? c0 : X0;
            fr.wd[1] = h ? c1 : X1;
            fr.wd[2] = h ? Y0 : c0;
            fr.wd[3] = h ? Y1 : c1;

            const __bf16* vp = vT_ws + ((size_t)b * DKV + lq) * SS
                               + kv + 16 * s + 8 * h;
            bf16x8 va0 = *(const bf16x8*)(vp);
            bf16x8 va1 = *(const bf16x8*)(vp + (size_t)32 * SS);
            oacc0 = __builtin_amdgcn_mfma_f32_32x32x16_bf16(va0, fr.v, oacc0, 0, 0, 0);
            oacc1 = __builtin_amdgcn_mfma_f32_32x32x16_bf16(va1, fr.v, oacc1, 0, 0, 0);
        }
    }

    l += __shfl_xor(l, 32);   // partner holds the other key-half's sum

    __syncthreads();          // everyone done with bias_lds-phase reads

    // ---- publish per-wave partials
    if (h == 0) { ml_lds[w][0][lq] = m; ml_lds[w][1][lq] = l; }
    #pragma unroll
    for (int r = 0; r < 16; r++) {
        const int v = (r & 3) + 8 * (r >> 2) + 4 * h;
        o_lds[w][lq][v]      = oacc0[r];
        o_lds[w][lq][32 + v] = oacc1[r];
    }
    __syncthreads();

    // ---- cross-wave flash combine: 2048 cells / 512 threads = 4 each
    for (int idx = threadIdx.x; idx < 32 * 64; idx += 512) {
        const int row = idx >> 6, col = idx & 63;
        float M = -3e38f;
        #pragma unroll
        for (int ww = 0; ww < NW; ww++) M = fmaxf(M, ml_lds[ww][0][row]);
        float L = 0.f, osum = 0.f;
        #pragma unroll
        for (int ww = 0; ww < NW; ww++) {
            const float a = exp2f((ml_lds[ww][0][row] - M) * CEXP);
            L += ml_lds[ww][1][row] * a;
            osum += o_lds[ww][row][col] * a;
        }
        out[((size_t)b * SS + qbase + row) * DKV + col] = osum / L;
    }
}

extern "C" void kernel_launch(void* const* d_in, const int* in_sizes, int n_in,
                              void* d_out, int out_size, void* d_ws, size_t ws_size,
                              hipStream_t stream)
{
    (void)in_sizes; (void)n_in; (void)out_size; (void)ws_size;
    const float* query = (const float*)d_in[0];
    const float* key_  = (const float*)d_in[1];
    const float* value = (const float*)d_in[2];
    const int*   mask  = (const int*)d_in[3];
    const float* Wq    = (const float*)d_in[4];
    const float* bq    = (const float*)d_in[5];
    const float* Wk    = (const float*)d_in[6];
    const float* bk    = (const float*)d_in[7];
    const float* Wv    = (const float*)d_in[8];
    const float* bv    = (const float*)d_in[9];
    float* out = (float*)d_out;

    __bf16* q_ws  = (__bf16*)d_ws;                         // 2 MB
    __bf16* k_ws  = q_ws + (size_t)BB * SS * DKV;          // 2 MB
    __bf16* vT_ws = k_ws + (size_t)BB * SS * DKV;          // 2 MB (transposed)
    __bf16* wf    = vT_ws + (size_t)BB * SS * DKV;         // 3 x 98 KB frag-W

    wconv_kernel<<<dim3(NCHUNK, 3, 1), 256, 0, stream>>>(Wq, Wk, Wv, wf);
    proj_kernel<<<dim3(256, 3, 1), 256, 0, stream>>>(
        query, key_, value, wf, bq, bk, bv, q_ws, k_ws, vT_ws);
    attn_kernel<<<dim3(SS / 32 * BB, 1, 1), 512, 0, stream>>>(
        q_ws, k_ws, vT_ws, mask, out);
}